// Round 4
// baseline (149.903 us; speedup 1.0000x reference)
//
#include <hip/hip_runtime.h>
#include <math.h>
#include <stdint.h>

// Problem constants (fixed by the reference):
//   z_e: (32, 64, 32, 32) fp32  -> N = 32768 rows of C = 64 (c-stride = 1024 floats)
//   embedding: (1024, 64) fp32
//   outputs flat: z_q_ste (2097152) | loss (1) | indices (32768, as float)
#define NUM_EMB 1024
#define DIM 64
#define LOSS_OFF 2097152
#define IDX_OFF 2097153
#define NROWS 32768
// Workspace: keys (32768 u64 = 256 KB) + norms (4 KB).
#define WS_KEYS_BYTES ((size_t)NROWS * sizeof(unsigned long long))
#define WS_NEEDED (WS_KEYS_BYTES + NUM_EMB * sizeof(float))

// Constant-address-space float: uniform-address loads compile to s_load
// (scalar cache -> SGPR). SGPR operands in v_fma avoid any vector-memory
// broadcast tax.
typedef __attribute__((address_space(4))) const float cfloat_t;

// numpy fp32 pairwise tail: fold 16 lanes -> scalar (8,4,2,1 XOR-fold).
// Bitwise-matches the verified summation of prior rounds.
__device__ __forceinline__ float np_fold16(float* y) {
#pragma unroll
    for (int j = 0; j < 8; ++j) y[j] = __fadd_rn(y[j], y[j + 8]);
#pragma unroll
    for (int j = 0; j < 4; ++j) y[j] = __fadd_rn(y[j], y[j + 4]);
    y[0] = __fadd_rn(y[0], y[2]);
    y[1] = __fadd_rn(y[1], y[3]);
    return __fadd_rn(y[0], y[1]);
}

// ---- Kernel 0: per-code |e_k|^2 (verified chain) + zero loss + init keys.
__global__ void vq_emb_norms(const float* __restrict__ emb,
                             float* __restrict__ norms,
                             unsigned long long* __restrict__ keys,
                             float* __restrict__ out) {
    int k = blockIdx.x * blockDim.x + threadIdx.x;   // 0..1023
    if (k == 0) out[LOSS_OFF] = 0.0f;
    // Init keys to the +inf sentinel for the atomicMin combine (coalesced).
    if (keys != nullptr) {
#pragma unroll
        for (int j = 0; j < NROWS / 1024; ++j)
            keys[j * 1024 + k] = ~0ull;
    }
    if (k < NUM_EMB) {
        const float4* e4 = reinterpret_cast<const float4*>(emb + k * DIM);
        float e2[DIM];
#pragma unroll
        for (int q = 0; q < 16; ++q) {
            const float4 v = e4[q];      // all 16 issued -> vmcnt-pipelined
            e2[q * 4 + 0] = v.x;
            e2[q * 4 + 1] = v.y;
            e2[q * 4 + 2] = v.z;
            e2[q * 4 + 3] = v.w;
        }
        float y[16];
#pragma unroll
        for (int j = 0; j < 16; ++j) {
            float a = __fadd_rn(__fmul_rn(e2[j],      e2[j]),
                                __fmul_rn(e2[j + 16], e2[j + 16]));
            float b = __fadd_rn(__fmul_rn(e2[j + 32], e2[j + 32]),
                                __fmul_rn(e2[j + 48], e2[j + 48]));
            y[j] = __fadd_rn(a, b);
        }
        norms[k] = np_fold16(y);
    }
}

// ---- Kernel 1: distance argmin, shared-code-stream structure ----
// Round-3 diagnosis: true VALU busy is ~36% (gfx94x VALUBusy formula
// overstates 2x on SIMD-32); the other ~64% is s_load latency. Cause: 16
// resident waves/CU each streamed a DIFFERENT 16KB code slice -> 256KB
// aggregate vs ~16KB scalar L1 -> every s_load missed to L2 (~300cy).
// Fix: 1024-thr blocks (16 waves); ALL 16 waves scan the SAME 64-code
// window (16KB -> fits scalar L1; first wave misses a line, 15 hit);
// each wave owns its own 64 rows (lane = row). Reg cap (z[64] in acc
// regs + ~40 arch = ~104 total -> 4 waves/SIMD) means exactly ONE block
// resident per CU -> one L1-resident scalar stream per CU. Grid 512 =
// 16 code-fractions (major) x 32 row-groups (minor): same-rg blocks sit
// 32 apart -> same XCD (32 % 8 == 0) -> z rows L2-hit on the second
// residency round. No __syncthreads in this kernel.
// Cross-fraction combine: atomicMin on packed u64 key
// (f32bits(d)<<32 | k): u64-min == np.argmin (d>0 -> monotone bits; ties
// -> lowest k); min is associative+commutative -> same winner as the
// verified single-kernel scan, independent of atomic order.
__global__ __launch_bounds__(1024, 4)
void vq_argmin(const float* __restrict__ z_e,
               const float* __restrict__ emb,
               const float* __restrict__ norms,
               unsigned long long* __restrict__ keys) {
    const int tid  = threadIdx.x;
    const int lane = tid & 63;
    const int wave = __builtin_amdgcn_readfirstlane(tid >> 6);  // 0..15

    const int frac = blockIdx.x >> 5;         // code window (16KB)
    const int rg   = blockIdx.x & 31;         // 1024-row group == batch b
    const int hw   = wave * 64 + lane;        // h*32+w inside the batch
    const long zbase = (long)rg * 65536 + hw; // z_e[b][c][hw] = zbase + c*1024
    const int row  = (rg << 10) + hw;         // global row index

    // Load this lane's z row (coalesced 256B per c).
    float z[DIM];
#pragma unroll
    for (int c = 0; c < DIM; ++c) z[c] = z_e[zbase + (long)c * 1024];

    // Keep z register-resident: empty asm is an identity with an opaque
    // result, so the loads can't be sunk into the code loop. Zero numerics
    // change -> correctness inherited from the verified rounds.
#pragma unroll
    for (int c = 0; c < DIM; ++c) asm volatile("" : "+v"(z[c]));

    // A = numpy-bitwise sum(z^2) (verified chain).
    float A;
    {
        float y[16];
#pragma unroll
        for (int j = 0; j < 16; ++j) {
            float a = __fadd_rn(__fmul_rn(z[j],      z[j]),
                                __fmul_rn(z[j + 16], z[j + 16]));
            float c2 = __fadd_rn(__fmul_rn(z[j + 32], z[j + 32]),
                                 __fmul_rn(z[j + 48], z[j + 48]));
            y[j] = __fadd_rn(a, c2);
        }
        A = np_fold16(y);
    }

    // Scalar-path views of the codebook + norms (uniform addresses).
    cfloat_t* E  = (cfloat_t*)(uintptr_t)emb;
    cfloat_t* Nr = (cfloat_t*)(uintptr_t)norms;

    unsigned long long best = ~0ull;
    const int kbase = frac * 64;              // 64 codes, ascending
    for (int kk = 0; kk < 64; kk += 2) {
        const int k0 = kbase + kk;
        cfloat_t* e0 = E + (size_t)k0 * DIM;
        // Serial ascending-c fmaf chain per code (bitwise == verified);
        // two independent chains fill VALU issue within the stall gaps.
        float dot0 = 0.f, dot1 = 0.f;
#pragma unroll
        for (int c = 0; c < DIM; ++c) {
            dot0 = __fmaf_rn(z[c], e0[c], dot0);
            dot1 = __fmaf_rn(z[c], e0[c + DIM], dot1);
        }
        // Reference rounding chain: d = fl(fl(A - 2*dot) + E_k)
        const float d0 = __fadd_rn(__fmaf_rn(-2.f, dot0, A), Nr[k0]);
        const float d1 = __fadd_rn(__fmaf_rn(-2.f, dot1, A), Nr[k0 + 1]);
        const unsigned long long key0 =
            ((unsigned long long)__float_as_uint(d0) << 32) | (unsigned)k0;
        const unsigned long long key1 =
            ((unsigned long long)__float_as_uint(d1) << 32) | (unsigned)(k0 + 1);
        if (key0 < best) best = key0;
        if (key1 < best) best = key1;
    }
    // One atomic per lane; 16 fractions contend lightly per row slot.
    atomicMin(&keys[row], best);
}

// ---- Kernel 2: finalize — indices + STE + loss ----
// 512 blocks x 512 thr, block = 64 rows: EXACT verified epilogue structure
// (8 waves x 8-c slices, per-wave shfl reduce, 8 partials summed, ONE
// atomic per 64-row block) -> bitwise-identical loss/STE/indices.
// Stream order guarantees keys are final.
__global__ __launch_bounds__(512, 4)
void vq_finalize(const float* __restrict__ z_e,
                 const float* __restrict__ emb,
                 const unsigned long long* __restrict__ keys,
                 float* __restrict__ out) {
    __shared__ int   s_final[64];
    __shared__ float s_loss[8];

    const int tid  = threadIdx.x;
    const int lane = tid & 63;
    const int wave = __builtin_amdgcn_readfirstlane(tid >> 6);

    const int n0 = blockIdx.x * 64;
    const int b  = n0 >> 10;
    const int hw = (n0 & 1023) + lane;
    const long zbase = (long)b * 65536 + hw;

    if (tid < 64) {
        const unsigned long long m = keys[n0 + tid];
        const int k = (int)(m & 0xFFFFFFFFu);
        s_final[tid] = k;
        out[IDX_OFF + n0 + tid] = (float)k;   // indices compared as float
    }
    __syncthreads();

    // STE + loss: wave w handles c in [w*8, w*8+8) for all 64 rows
    // (lane = row keeps loads/stores coalesced). Verified chain.
    const int fidx = s_final[lane];
    float lsum = 0.f;
#pragma unroll
    for (int j = 0; j < DIM / 8; ++j) {
        const int c = wave * 8 + j;
        const float zc = z_e[zbase + (long)c * 1024];   // L2-hot
        const float ec = emb[fidx * DIM + c];           // per-lane gather
        out[((long)(b * 64 + c)) * 1024 + hw] = zc + (ec - zc);  // STE forward
        const float dlt = zc - ec;
        lsum = __fmaf_rn(dlt, dlt, lsum);
    }
#pragma unroll
    for (int off = 32; off >= 1; off >>= 1) lsum += __shfl_xor(lsum, off, 64);
    if (lane == 0) s_loss[wave] = lsum;
    __syncthreads();

    // ONE atomic per 64-row block (identical grouping to round-0).
    if (tid == 0) {
        float t = 0.f;
#pragma unroll
        for (int w = 0; w < 8; ++w) t = __fadd_rn(t, s_loss[w]);
        // 0.25 / 2097152 = 2^-23 exactly
        atomicAdd(out + LOSS_OFF, t * 1.1920928955078125e-07f);
    }
}

// ---- Fallback (small workspace): the verified round-0 fused kernel ----
// Needs just 4 KB (norms). Measured 91 us/dispatch; bitwise-verified.
__global__ __launch_bounds__(512, 4)
void vq_fused(const float* __restrict__ z_e,
              const float* __restrict__ emb,
              const float* __restrict__ norms,
              float* __restrict__ out) {
    __shared__ unsigned long long s_keys[8 * 64];
    __shared__ int   s_final[64];
    __shared__ float s_loss[8];

    const int tid  = threadIdx.x;
    const int lane = tid & 63;
    const int wave = __builtin_amdgcn_readfirstlane(tid >> 6);

    const int n0 = blockIdx.x * 64;
    const int b  = n0 >> 10;
    const int hw = (n0 & 1023) + lane;
    const long zbase = (long)b * 65536 + hw;

    float z[DIM];
#pragma unroll
    for (int c = 0; c < DIM; ++c) z[c] = z_e[zbase + (long)c * 1024];
#pragma unroll
    for (int c = 0; c < DIM; ++c) asm volatile("" : "+v"(z[c]));

    float A;
    {
        float y[16];
#pragma unroll
        for (int j = 0; j < 16; ++j) {
            float a = __fadd_rn(__fmul_rn(z[j],      z[j]),
                                __fmul_rn(z[j + 16], z[j + 16]));
            float c2 = __fadd_rn(__fmul_rn(z[j + 32], z[j + 32]),
                                 __fmul_rn(z[j + 48], z[j + 48]));
            y[j] = __fadd_rn(a, c2);
        }
        A = np_fold16(y);
    }

    cfloat_t* E  = (cfloat_t*)(uintptr_t)emb;
    cfloat_t* Nr = (cfloat_t*)(uintptr_t)norms;

    unsigned long long best = ~0ull;
    const int kbase = wave * (NUM_EMB / 8);
    for (int kk = 0; kk < NUM_EMB / 8; kk += 2) {
        const int k0 = kbase + kk;
        cfloat_t* e0 = E + (size_t)k0 * DIM;
        cfloat_t* e1 = e0 + DIM;
        float dot0 = 0.f, dot1 = 0.f;
#pragma unroll
        for (int c = 0; c < DIM; ++c) {
            dot0 = __fmaf_rn(z[c], e0[c], dot0);
            dot1 = __fmaf_rn(z[c], e1[c], dot1);
        }
        const float d0 = __fadd_rn(__fmaf_rn(-2.f, dot0, A), Nr[k0]);
        const float d1 = __fadd_rn(__fmaf_rn(-2.f, dot1, A), Nr[k0 + 1]);
        const unsigned long long key0 =
            ((unsigned long long)__float_as_uint(d0) << 32) | (unsigned)k0;
        const unsigned long long key1 =
            ((unsigned long long)__float_as_uint(d1) << 32) | (unsigned)(k0 + 1);
        if (key0 < best) best = key0;
        if (key1 < best) best = key1;
    }
    s_keys[wave * 64 + lane] = best;
    __syncthreads();

    if (tid < 64) {
        unsigned long long m = s_keys[tid];
#pragma unroll
        for (int w = 1; w < 8; ++w) {
            unsigned long long t = s_keys[w * 64 + tid];
            if (t < m) m = t;
        }
        const int k = (int)(m & 0xFFFFFFFFu);
        s_final[tid] = k;
        out[IDX_OFF + n0 + tid] = (float)k;
    }
    __syncthreads();

    const int fidx = s_final[lane];
    float lsum = 0.f;
#pragma unroll
    for (int j = 0; j < DIM / 8; ++j) {
        const int c = wave * 8 + j;
        const float zc = z_e[zbase + (long)c * 1024];
        const float ec = emb[fidx * DIM + c];
        out[((long)(b * 64 + c)) * 1024 + hw] = zc + (ec - zc);
        const float dlt = zc - ec;
        lsum = __fmaf_rn(dlt, dlt, lsum);
    }
#pragma unroll
    for (int off = 32; off >= 1; off >>= 1) lsum += __shfl_xor(lsum, off, 64);
    if (lane == 0) s_loss[wave] = lsum;
    __syncthreads();

    if (tid == 0) {
        float t = 0.f;
#pragma unroll
        for (int w = 0; w < 8; ++w) t = __fadd_rn(t, s_loss[w]);
        atomicAdd(out + LOSS_OFF, t * 1.1920928955078125e-07f);
    }
}

extern "C" void kernel_launch(void* const* d_in, const int* in_sizes, int n_in,
                              void* d_out, int out_size, void* d_ws, size_t ws_size,
                              hipStream_t stream) {
    const float* z_e = (const float*)d_in[0];
    const float* emb = (const float*)d_in[1];
    float* out = (float*)d_out;

    if (ws_size >= WS_NEEDED) {
        unsigned long long* keys = (unsigned long long*)d_ws;
        float* norms = (float*)((char*)d_ws + WS_KEYS_BYTES);
        // norms kernel also zeroes out[LOSS_OFF] and inits keys
        // (stream-ordered ahead of the atomics that use them).
        vq_emb_norms<<<dim3(16), dim3(64), 0, stream>>>(emb, norms, keys, out);
        vq_argmin<<<dim3(512), dim3(1024), 0, stream>>>(z_e, emb, norms, keys);
        vq_finalize<<<dim3(512), dim3(512), 0, stream>>>(z_e, emb, keys, out);
    } else {
        // Small workspace: verified single fused kernel (4 KB norms only).
        float* norms = (float*)d_ws;
        vq_emb_norms<<<dim3(16), dim3(64), 0, stream>>>(emb, norms, nullptr, out);
        vq_fused<<<dim3(32768 / 64), dim3(512), 0, stream>>>(z_e, emb, norms, out);
    }
}